// Round 12
// baseline (272.914 us; speedup 1.0000x reference)
//
#include <hip/hip_runtime.h>
#include <math.h>

#define QUEUE 8192
#define BATCH 256
#define NROW  8448        // QUEUE + BATCH
#define DIM   512
#define NCLS  65
#define KNB   10
#define NCAND 16          // rescored candidate set per row
#define BM 128
#define BN 128
#define BK2 64            // K-step (two 32-deep MFMA halves)
#define NBAND  66         // NROW / BM
#define NCHUNK 66         // NROW / BN
#define NTRI  2211        // NBAND*(NBAND+1)/2 upper-triangle tiles
#define CAP 128           // candidate slots per row
#define HCAP (1 << 19)    // global hit-list capacity (expect ~230K)
#define THR 0.11f         // bf16-sim candidate threshold (~40 sigma margin vs true 10th)

typedef __attribute__((ext_vector_type(8))) short bf16x8;
typedef __attribute__((ext_vector_type(4))) float f32x4;

__device__ __forceinline__ unsigned short f2bf(float f) {
    unsigned int u = __float_as_uint(f);
    unsigned int r = (u + 0x7fffu + ((u >> 16) & 1u)) >> 16;   // RTNE
    return (unsigned short)r;
}

// async global->LDS, 16B per lane; dest = wave-uniform base + lane*16 (linear)
__device__ __forceinline__ void gl16(const unsigned short* g, unsigned short* l) {
    __builtin_amdgcn_global_load_lds(
        (const __attribute__((address_space(1))) unsigned int*)g,
        (__attribute__((address_space(3))) unsigned int*)l, 16, 0, 0);
}

// ---------------- kernel 1: row normalize (fp32 + bf16 copies) ----------------
__global__ __launch_bounds__(128) void k_norm(const float* __restrict__ mem,
                                              const float* __restrict__ xq,
                                              float* __restrict__ sn,
                                              unsigned short* __restrict__ snb) {
    int row = blockIdx.x;
    const float* src = (row < QUEUE) ? (mem + (size_t)row * DIM)
                                     : (xq + (size_t)(row - QUEUE) * DIM);
    float4 v = reinterpret_cast<const float4*>(src)[threadIdx.x];
    float ss = v.x*v.x + v.y*v.y + v.z*v.z + v.w*v.w;
    #pragma unroll
    for (int o = 32; o > 0; o >>= 1) ss += __shfl_xor(ss, o);
    __shared__ float s2[2];
    if ((threadIdx.x & 63) == 0) s2[threadIdx.x >> 6] = ss;
    __syncthreads();
    float nrm = fmaxf(sqrtf(s2[0] + s2[1]), 1e-12f);
    float4 o4 = make_float4(v.x / nrm, v.y / nrm, v.z / nrm, v.w / nrm);
    reinterpret_cast<float4*>(sn + (size_t)row * DIM)[threadIdx.x] = o4;
    ushort4 b4;
    b4.x = f2bf(o4.x); b4.y = f2bf(o4.y); b4.z = f2bf(o4.z); b4.w = f2bf(o4.w);
    reinterpret_cast<ushort4*>(snb + (size_t)row * DIM)[threadIdx.x] = b4;
}

// ---------------- kernel 2: bf16 MFMA sim, UPPER-TRIANGLE tiles, pipelined K-loop.
// Harvest: wave-aggregated append to a single global hit list (1 atomic/wave).
__global__ __launch_bounds__(256, 4) void k_simscan(const unsigned short* __restrict__ snb,
                                                    float* __restrict__ hv,
                                                    unsigned int* __restrict__ hij,
                                                    int* __restrict__ gh) {
    __shared__ unsigned short Bbuf[2][BN][BK2];   // 2 x 16 KB, linear

    // bijective XCD-contiguous remap (m204) over triangular index
    int wg = blockIdx.x;
    {
        const int q = NTRI / 8, r = NTRI % 8;     // 276, 3
        int x = wg & 7, idx = wg >> 3;
        wg = (x < r ? x * (q + 1) : r * (q + 1) + (x - r) * q) + idx;
    }
    // triangular decode: band b pairs with chunks b..NBAND-1
    int band = 0, rem = wg;
    while (rem >= NCHUNK - band) { rem -= NCHUNK - band; ++band; }
    int chunk = band + rem;
    int i0 = band * BM;
    int c0 = chunk * BN;

    int tid  = threadIdx.x;
    int w    = tid >> 6;
    int lane = tid & 63;
    int lr   = lane & 15;
    int g    = lane >> 4;       // 0..3

    int grow0 = i0 + 32*w + lr;       // row owned for h=0
    int grow1 = grow0 + 16;           // row owned for h=1
    const unsigned short* gA0 = snb + (size_t)grow0 * DIM + 8*g;
    const unsigned short* gA1 = snb + (size_t)grow1 * DIM + 8*g;

    // staging source: lane l fetches B[c0 + 32w + 8j + (l>>3)][ ((l&7)^(l>>3))*8 .. +8 ]
    const unsigned short* gB = snb + (size_t)(c0 + 32*w + (lane >> 3)) * DIM
                                   + ((lane & 7) ^ (lane >> 3)) * 8;
    // read-side swizzled slot offsets (elements)
    const int off0e = ((g ^ (lr & 7)) * 8);
    const int off1e = off0e ^ 32;

    f32x4 acc[2][8];
    #pragma unroll
    for (int n = 0; n < 8; ++n) {
        acc[0][n] = (f32x4){0.f,0.f,0.f,0.f};
        acc[1][n] = (f32x4){0.f,0.f,0.f,0.f};
    }

    // prologue: stage k-tile 0 into buf 0 + A(0) into reg set 0
    {
        unsigned short* dst = &Bbuf[0][32*w][0];
        gl16(gB,            dst);
        gl16(gB +  8*DIM,   dst +  8*BK2);
        gl16(gB + 16*DIM,   dst + 16*BK2);
        gl16(gB + 24*DIM,   dst + 24*BK2);
    }
    bf16x8 aA[2][4];
    aA[0][0] = *reinterpret_cast<const bf16x8*>(gA0);
    aA[0][1] = *reinterpret_cast<const bf16x8*>(gA0 + 32);
    aA[0][2] = *reinterpret_cast<const bf16x8*>(gA1);
    aA[0][3] = *reinterpret_cast<const bf16x8*>(gA1 + 32);
    __syncthreads();   // full drain: buf0 + A(0) valid

    #pragma unroll
    for (int it = 0; it < 8; ++it) {
        const int cur = it & 1, nxt = cur ^ 1;
        if (it > 0) {
            asm volatile("s_waitcnt vmcnt(0)" ::: "memory");
            __builtin_amdgcn_sched_barrier(0);
            __builtin_amdgcn_s_barrier();
            __builtin_amdgcn_sched_barrier(0);
        }
        if (it < 7) {   // issue next tile's stage + A loads; drained top of next iter
            unsigned short* dst = &Bbuf[nxt][32*w][0];
            const unsigned short* src = gB + (it + 1) * BK2;
            gl16(src,            dst);
            gl16(src +  8*DIM,   dst +  8*BK2);
            gl16(src + 16*DIM,   dst + 16*BK2);
            gl16(src + 24*DIM,   dst + 24*BK2);
            const int k1 = (it + 1) * BK2;
            aA[nxt][0] = *reinterpret_cast<const bf16x8*>(gA0 + k1);
            aA[nxt][1] = *reinterpret_cast<const bf16x8*>(gA0 + k1 + 32);
            aA[nxt][2] = *reinterpret_cast<const bf16x8*>(gA1 + k1);
            aA[nxt][3] = *reinterpret_cast<const bf16x8*>(gA1 + k1 + 32);
        }
        const unsigned short* Bb = &Bbuf[cur][0][0];
        #pragma unroll
        for (int n = 0; n < 8; ++n) {
            const unsigned short* rbase = Bb + (16*n + lr) * BK2;
            bf16x8 b0 = *reinterpret_cast<const bf16x8*>(rbase + off0e);
            bf16x8 b1 = *reinterpret_cast<const bf16x8*>(rbase + off1e);
            acc[0][n] = __builtin_amdgcn_mfma_f32_16x16x32_bf16(b0, aA[cur][0], acc[0][n], 0, 0, 0);
            acc[1][n] = __builtin_amdgcn_mfma_f32_16x16x32_bf16(b0, aA[cur][2], acc[1][n], 0, 0, 0);
            acc[0][n] = __builtin_amdgcn_mfma_f32_16x16x32_bf16(b1, aA[cur][1], acc[0][n], 0, 0, 0);
            acc[1][n] = __builtin_amdgcn_mfma_f32_16x16x32_bf16(b1, aA[cur][3], acc[1][n], 0, 0, 0);
        }
    }

    // ---- wave-aggregated harvest: count -> prefix-sum -> 1 atomic/wave -> stores.
    // gc > grow covers both off-diag (always true) and diag (upper half, no self).
    int nh = 0;
    #pragma unroll
    for (int h = 0; h < 2; ++h) {
        int grow = h ? grow1 : grow0;
        #pragma unroll
        for (int n = 0; n < 8; ++n) {
            f32x4 v4 = acc[h][n];
            #pragma unroll
            for (int e = 0; e < 4; ++e) {
                int gc = c0 + 16*n + 4*g + e;
                nh += (v4[e] > THR && gc > grow) ? 1 : 0;
            }
        }
    }
    int scan = nh;
    #pragma unroll
    for (int o = 1; o < 64; o <<= 1) {
        int u = __shfl_up(scan, o);
        if (lane >= o) scan += u;
    }
    int wtot = __shfl(scan, 63);
    int base = 0;
    if (lane == 63 && wtot > 0) base = atomicAdd(gh, wtot);
    base = __shfl(base, 63);
    int t = base + scan - nh;           // exclusive prefix
    if (nh) {
        #pragma unroll
        for (int h = 0; h < 2; ++h) {
            int grow = h ? grow1 : grow0;
            #pragma unroll
            for (int n = 0; n < 8; ++n) {
                f32x4 v4 = acc[h][n];
                #pragma unroll
                for (int e = 0; e < 4; ++e) {
                    float v = v4[e]; int gc = c0 + 16*n + 4*g + e;
                    if (v > THR && gc > grow) {
                        if (t < HCAP) {
                            hv[t]  = v;
                            hij[t] = ((unsigned)grow << 14) | (unsigned)gc;
                        }
                        ++t;
                    }
                }
            }
        }
    }
}

// ---------------- kernel 2b: scatter hits to both rows' candidate lists ----------------
__global__ __launch_bounds__(256) void k_scatter(const float* __restrict__ hv,
                                                 const unsigned int* __restrict__ hij,
                                                 const int* __restrict__ gh,
                                                 float* __restrict__ cval,
                                                 int* __restrict__ cidx,
                                                 int* __restrict__ cnt) {
    int n = *gh; if (n > HCAP) n = HCAP;
    for (int t = blockIdx.x * 256 + threadIdx.x; t < n; t += gridDim.x * 256) {
        float v = hv[t];
        unsigned p = hij[t];
        int i = (int)(p >> 14), j = (int)(p & 16383u);
        int s = atomicAdd(&cnt[i], 1);
        if (s < CAP) { cval[(size_t)i * CAP + s] = v; cidx[(size_t)i * CAP + s] = j; }
        int s2 = atomicAdd(&cnt[j], 1);
        if (s2 < CAP) { cval[(size_t)j * CAP + s2] = v; cidx[(size_t)j * CAP + s2] = i; }
    }
}

// ---------------- kernel 3: fused top-16 select + fp32 rescore + GNN pass 1 ----------------
__global__ __launch_bounds__(256) void k_selgnn1(const float* __restrict__ cval,
                                                 const int* __restrict__ cidx,
                                                 const int* __restrict__ cnt,
                                                 const float* __restrict__ sn,
                                                 const long long* __restrict__ labels,
                                                 const float* __restrict__ Wm,
                                                 float* __restrict__ wv,
                                                 int* __restrict__ wi,
                                                 float* __restrict__ h0) {
    int wq = threadIdx.x >> 6, lane = threadIdx.x & 63;
    int row = blockIdx.x * 4 + wq;
    int nc = cnt[row]; if (nc > CAP) nc = CAP;
    const float* pv = cval + (size_t)row * CAP;
    const int*   pi = cidx + (size_t)row * CAP;
    float s0v = (lane < nc) ? pv[lane] : -1e30f;
    int   s0i = (lane < nc) ? pi[lane] : 0x7fffffff;
    float s1v = (lane + 64 < nc) ? pv[lane + 64] : -1e30f;
    int   s1i = (lane + 64 < nc) ? pi[lane + 64] : 0x7fffffff;

    // ---- tournament top-16 (wave-uniform result in cwv/cwi) ----
    float cwv[NCAND]; int cwi[NCAND];
    #pragma unroll
    for (int t = 0; t < NCAND; ++t) {
        bool p0 = (s0v > s1v) || (s0v == s1v && s0i < s1i);
        float bv = p0 ? s0v : s1v;
        int   bi = p0 ? s0i : s1i;
        #pragma unroll
        for (int o = 32; o > 0; o >>= 1) {
            float ov = __shfl_xor(bv, o);
            int   oi = __shfl_xor(bi, o);
            if (ov > bv || (ov == bv && oi < bi)) { bv = ov; bi = oi; }
        }
        cwv[t] = bv; cwi[t] = bi;
        if (s0i == bi) { s0v = -1e30f; s0i = 0x7fffffff; }
        if (s1i == bi) { s1v = -1e30f; s1i = 0x7fffffff; }
    }

    // ---- exact fp32 rescore: group q = lane>>4 handles candidate 4j+q in round j
    int qg = lane >> 4, r = lane & 15;
    float4 qv[8];
    #pragma unroll
    for (int u = 0; u < 8; ++u)
        qv[u] = *reinterpret_cast<const float4*>(sn + (size_t)row * DIM + 32*r + 4*u);

    float scJ[4]; int idJ[4];
    #pragma unroll
    for (int j = 0; j < 4; ++j) {
        float v_j = (qg == 0) ? cwv[4*j+0] : (qg == 1) ? cwv[4*j+1]
                  : (qg == 2) ? cwv[4*j+2] : cwv[4*j+3];
        int   i_j = (qg == 0) ? cwi[4*j+0] : (qg == 1) ? cwi[4*j+1]
                  : (qg == 2) ? cwi[4*j+2] : cwi[4*j+3];
        bool valid = (v_j > -1e29f);
        int cid = valid ? i_j : row;
        const float* cp = sn + (size_t)cid * DIM + 32*r;
        float d = 0.f;
        #pragma unroll
        for (int u = 0; u < 8; ++u) {
            float4 a = *reinterpret_cast<const float4*>(cp + 4*u);
            d += qv[u].x*a.x + qv[u].y*a.y + qv[u].z*a.z + qv[u].w*a.w;
        }
        d += __shfl_xor(d, 1); d += __shfl_xor(d, 2);
        d += __shfl_xor(d, 4); d += __shfl_xor(d, 8);
        scJ[j] = valid ? d : -1e30f;
        idJ[j] = i_j;
    }
    // redistribute: lane t<16 takes candidate t (round t>>2, group t&3)
    int srcl = 16 * (lane & 3);
    float rs0 = __shfl(scJ[0], srcl), rs1 = __shfl(scJ[1], srcl);
    float rs2 = __shfl(scJ[2], srcl), rs3 = __shfl(scJ[3], srcl);
    int   ri0 = __shfl(idJ[0], srcl), ri1 = __shfl(idJ[1], srcl);
    int   ri2 = __shfl(idJ[2], srcl), ri3 = __shfl(idJ[3], srcl);
    int jj = (lane >> 2) & 3;
    float dmine = (jj == 0) ? rs0 : (jj == 1) ? rs1 : (jj == 2) ? rs2 : rs3;
    int   cmine = (jj == 0) ? ri0 : (jj == 1) ? ri1 : (jj == 2) ? ri2 : ri3;

    int rank = 0;
    #pragma unroll
    for (int j = 0; j < NCAND; ++j) {
        float dj = __shfl(dmine, j);
        int   cj = __shfl(cmine, j);
        if (dj > dmine || (dj == dmine && cj < cmine)) ++rank;
    }
    if (lane < NCAND && rank < KNB && dmine > -1e29f) {
        wv[(size_t)row * KNB + rank] = dmine;
        wi[(size_t)row * KNB + rank] = cmine;
    }

    // ---- GNN pass 1 (implicit one-hot): a[c] = sum_k wk * [label(id_k)==c] ----
    float a = 0.f, a64 = 0.f;
    #pragma unroll
    for (int t = 0; t < NCAND; ++t) {
        float d  = __shfl(dmine, t);
        int   id = __shfl(cmine, t);
        int   rk = __shfl(rank, t);
        if (rk < KNB && d > -1e29f && id < QUEUE) {
            int lbl = (int)labels[id];
            a   += (lbl == lane) ? d : 0.f;
            a64 += (lbl == 64)   ? d : 0.f;
        }
    }
    float l = 0.f, l64 = 0.f;
    #pragma unroll 8
    for (int cc = 0; cc < 64; ++cc) {
        float ac = __shfl(a, cc);
        l   = fmaf(ac, Wm[cc * NCLS + lane], l);
        l64 = fmaf(ac, Wm[cc * NCLS + 64],  l64);
    }
    l   = fmaf(a64, Wm[64 * NCLS + lane], l);
    l64 = fmaf(a64, Wm[64 * NCLS + 64],  l64);
    float m = l;
    #pragma unroll
    for (int o = 32; o > 0; o >>= 1) m = fmaxf(m, __shfl_xor(m, o));
    m = fmaxf(m, l64);
    float e = expf(l - m);
    float s = e;
    #pragma unroll
    for (int o = 32; o > 0; o >>= 1) s += __shfl_xor(s, o);
    float e64 = expf(l64 - m);
    s += e64;
    h0[(size_t)row * NCLS + lane] = e / s;
    if (lane == 0) h0[(size_t)row * NCLS + 64] = e64 / s;
}

// ---------------- kernel 4: GNN pass 2, ONLY for query-neighbor rows ----------------
// wave p handles pair (q = p/10, k = p%10): row = wi[(QUEUE+q)*KNB + k].
// Duplicate rows recompute identical values (benign).
__global__ __launch_bounds__(256) void k_gnnw(const float* __restrict__ wv,
                                              const int* __restrict__ wi,
                                              const float* __restrict__ hin,
                                              const float* __restrict__ Wm,
                                              float* __restrict__ hout) {
    int wq = threadIdx.x >> 6, lane = threadIdx.x & 63;
    int p = blockIdx.x * 4 + wq;               // 0..2559
    int q = p / KNB, k2 = p - q * KNB;
    int row = wi[(size_t)(QUEUE + q) * KNB + k2];
    float a = 0.f, a64 = 0.f;
    #pragma unroll
    for (int k = 0; k < KNB; ++k) {
        float wk = wv[(size_t)row * KNB + k];
        int   id = wi[(size_t)row * KNB + k];
        a += wk * hin[(size_t)id * NCLS + lane];
        if (lane == 0) a64 += wk * hin[(size_t)id * NCLS + 64];
    }
    a64 = __shfl(a64, 0);
    float l = 0.f, l64 = 0.f;
    #pragma unroll 8
    for (int cc = 0; cc < 64; ++cc) {
        float ac = __shfl(a, cc);
        l   = fmaf(ac, Wm[cc * NCLS + lane], l);
        l64 = fmaf(ac, Wm[cc * NCLS + 64],  l64);
    }
    l   = fmaf(a64, Wm[64 * NCLS + lane], l);
    l64 = fmaf(a64, Wm[64 * NCLS + 64],  l64);
    float m = l;
    #pragma unroll
    for (int o = 32; o > 0; o >>= 1) m = fmaxf(m, __shfl_xor(m, o));
    m = fmaxf(m, l64);
    float e = expf(l - m);
    float s = e;
    #pragma unroll
    for (int o = 32; o > 0; o >>= 1) s += __shfl_xor(s, o);
    float e64 = expf(l64 - m);
    s += e64;
    hout[(size_t)row * NCLS + lane] = e / s;
    if (lane == 0) hout[(size_t)row * NCLS + 64] = e64 / s;
}

// ---------------- kernel 5: final pass (queries) + confidence/argmax ----------------
__global__ __launch_bounds__(256) void k_finalw(const float* __restrict__ wv,
                                                const int* __restrict__ wi,
                                                const float* __restrict__ hin,
                                                const float* __restrict__ Wm,
                                                float* __restrict__ out) {
    int wq = threadIdx.x >> 6, lane = threadIdx.x & 63;
    int qi = blockIdx.x * 4 + wq;
    int row = QUEUE + qi;
    float a = 0.f, a64 = 0.f;
    #pragma unroll
    for (int k = 0; k < KNB; ++k) {
        float wk = wv[(size_t)row * KNB + k];
        int   id = wi[(size_t)row * KNB + k];
        a += wk * hin[(size_t)id * NCLS + lane];
        if (lane == 0) a64 += wk * hin[(size_t)id * NCLS + 64];
    }
    a64 = __shfl(a64, 0);
    float l = 0.f, l64 = 0.f;
    #pragma unroll 8
    for (int cc = 0; cc < 64; ++cc) {
        float ac = __shfl(a, cc);
        l   = fmaf(ac, Wm[cc * NCLS + lane], l);
        l64 = fmaf(ac, Wm[cc * NCLS + 64],  l64);
    }
    l   = fmaf(a64, Wm[64 * NCLS + lane], l);
    l64 = fmaf(a64, Wm[64 * NCLS + 64],  l64);
    float bv = l; int bi = lane;
    #pragma unroll
    for (int o = 32; o > 0; o >>= 1) {
        float ov = __shfl_xor(bv, o);
        int   oi = __shfl_xor(bi, o);
        if (ov > bv || (ov == bv && oi < bi)) { bv = ov; bi = oi; }
    }
    if (l64 > bv) { bv = l64; bi = 64; }
    float e = expf(l - bv);
    float s = e;
    #pragma unroll
    for (int o = 32; o > 0; o >>= 1) s += __shfl_xor(s, o);
    s += expf(l64 - bv);
    if (lane == 0) {
        out[qi]         = 1.0f / s;     // confidence = max(softmax)
        out[BATCH + qi] = (float)bi;    // predict
    }
}

// ---------------- host launcher ----------------
extern "C" void kernel_launch(void* const* d_in, const int* in_sizes, int n_in,
                              void* d_out, int out_size, void* d_ws, size_t ws_size,
                              hipStream_t stream) {
    const float*     x      = (const float*)d_in[0];      // (256,512)
    const float*     memory = (const float*)d_in[1];      // (8192,512)
    const float*     W      = (const float*)d_in[2];      // (65,65)
    const long long* labels = (const long long*)d_in[3];  // (8192,)

    float*          sn  = (float*)d_ws;                                    // NROW*DIM f32
    unsigned short* snb = (unsigned short*)(sn + (size_t)NROW * DIM);      // NROW*DIM bf16
    float* cval = (float*)(snb + (size_t)NROW * DIM);                      // NROW*CAP
    int*   cidx = (int*)(cval + (size_t)NROW * CAP);                       // NROW*CAP
    int*   cnt  = (int*)(cidx + (size_t)NROW * CAP);                       // NROW
    int*   gh   = cnt + NROW;                                              // 1 (+3 pad)
    float* hv   = (float*)(gh + 4);                                        // HCAP
    unsigned int* hij = (unsigned int*)(hv + HCAP);                        // HCAP
    float* wv   = (float*)(hij + HCAP);                                    // NROW*KNB
    int*   wi   = (int*)(wv + (size_t)NROW * KNB);                         // NROW*KNB
    float* h0   = (float*)(wi + (size_t)NROW * KNB);                       // NROW*NCLS
    float* h1   = h0 + (size_t)NROW * NCLS;                                // NROW*NCLS

    hipMemsetAsync(cnt, 0, (NROW + 4) * sizeof(int), stream);   // cnt + gh
    k_norm<<<NROW, 128, 0, stream>>>(memory, x, sn, snb);
    k_simscan<<<NTRI, 256, 0, stream>>>(snb, hv, hij, gh);
    k_scatter<<<512, 256, 0, stream>>>(hv, hij, gh, cval, cidx, cnt);
    k_selgnn1<<<NROW / 4, 256, 0, stream>>>(cval, cidx, cnt, sn, labels, W, wv, wi, h0);
    k_gnnw<<<640, 256, 0, stream>>>(wv, wi, h0, W, h1);
    k_finalw<<<BATCH / 4, 256, 0, stream>>>(wv, wi, h1, W, (float*)d_out);
}

// Round 13
// 231.290 us; speedup vs baseline: 1.1800x; 1.1800x over previous
//
#include <hip/hip_runtime.h>
#include <math.h>

#define QUEUE 8192
#define BATCH 256
#define NROW  8448        // QUEUE + BATCH
#define DIM   512
#define NCLS  65
#define KNB   10
#define NCAND 16          // rescored candidate set per row
#define BM 128
#define BN 128
#define BK2 64            // K-step (two 32-deep MFMA halves)
#define NBAND  66         // NROW / BM
#define NTRI  2211        // NBAND*(NBAND+1)/2 upper-triangle tiles
#define GSB 11            // supertile edge (tiles); 6 supergroups of 11 bands
#define CAP 128           // candidate slots per row
#define THR 0.11f         // bf16-sim candidate threshold (~40 sigma margin vs true 10th)

typedef __attribute__((ext_vector_type(8))) short bf16x8;
typedef __attribute__((ext_vector_type(4))) float f32x4;

__device__ __forceinline__ unsigned short f2bf(float f) {
    unsigned int u = __float_as_uint(f);
    unsigned int r = (u + 0x7fffu + ((u >> 16) & 1u)) >> 16;   // RTNE
    return (unsigned short)r;
}

// async global->LDS, 16B per lane; dest = wave-uniform base + lane*16 (linear)
__device__ __forceinline__ void gl16(const unsigned short* g, unsigned short* l) {
    __builtin_amdgcn_global_load_lds(
        (const __attribute__((address_space(1))) unsigned int*)g,
        (__attribute__((address_space(3))) unsigned int*)l, 16, 0, 0);
}

// ---------------- kernel 1: row normalize (fp32 + bf16 copies) ----------------
__global__ __launch_bounds__(128) void k_norm(const float* __restrict__ mem,
                                              const float* __restrict__ xq,
                                              float* __restrict__ sn,
                                              unsigned short* __restrict__ snb) {
    int row = blockIdx.x;
    const float* src = (row < QUEUE) ? (mem + (size_t)row * DIM)
                                     : (xq + (size_t)(row - QUEUE) * DIM);
    float4 v = reinterpret_cast<const float4*>(src)[threadIdx.x];
    float ss = v.x*v.x + v.y*v.y + v.z*v.z + v.w*v.w;
    #pragma unroll
    for (int o = 32; o > 0; o >>= 1) ss += __shfl_xor(ss, o);
    __shared__ float s2[2];
    if ((threadIdx.x & 63) == 0) s2[threadIdx.x >> 6] = ss;
    __syncthreads();
    float nrm = fmaxf(sqrtf(s2[0] + s2[1]), 1e-12f);
    float4 o4 = make_float4(v.x / nrm, v.y / nrm, v.z / nrm, v.w / nrm);
    reinterpret_cast<float4*>(sn + (size_t)row * DIM)[threadIdx.x] = o4;
    ushort4 b4;
    b4.x = f2bf(o4.x); b4.y = f2bf(o4.y); b4.z = f2bf(o4.z); b4.w = f2bf(o4.w);
    reinterpret_cast<ushort4*>(snb + (size_t)row * DIM)[threadIdx.x] = b4;
}

// ---------------- kernel 2: bf16 MFMA sim, upper triangle, SUPERTILE-ordered for L2.
// Supertiles of 11x11 tiles: 6 diagonal (66 tiles) then 15 off-diag (121 tiles).
// Footprint/supertile 1.4-2.8 MB << 4 MB per-XCD L2 -> prefetch window stays L2-hot.
// K-loop: r11 pipelined form (vmcnt(0)+raw barrier at top, issue t+1, MFMA on t).
__global__ __launch_bounds__(256, 4) void k_simscan(const unsigned short* __restrict__ snb,
                                                    float* __restrict__ cval,
                                                    int* __restrict__ cidx,
                                                    int* __restrict__ cnt) {
    __shared__ unsigned short Bbuf[2][BN][BK2];   // 2 x 16 KB, linear

    // bijective XCD-contiguous remap (m204)
    int wg = blockIdx.x;
    {
        const int q = NTRI / 8, r = NTRI % 8;     // 276, 3
        int x = wg & 7, idx = wg >> 3;
        wg = (x < r ? x * (q + 1) : r * (q + 1) + (x - r) * q) + idx;
    }
    // supertile decode (G=11): wg<396 -> diagonal supertile (triangular inner);
    // else off-diagonal supertile pair (I<J), 121 inner tiles.
    int band, chunk;
    if (wg < 6 * 66) {
        int I = wg / 66, t = wg % 66;
        int r2 = 0;
        while (t >= GSB - r2) { t -= GSB - r2; ++r2; }
        band  = I * GSB + r2;
        chunk = band + t;
    } else {
        int e = (wg - 396) / 121, t = (wg - 396) % 121;
        int I = 0, rem = e;
        while (rem >= 5 - I) { rem -= 5 - I; ++I; }
        int J = I + 1 + rem;
        band  = I * GSB + t / GSB;
        chunk = J * GSB + t % GSB;
    }
    int i0 = band * BM;
    int c0 = chunk * BN;

    int tid  = threadIdx.x;
    int w    = tid >> 6;
    int lane = tid & 63;
    int lr   = lane & 15;
    int g    = lane >> 4;       // 0..3

    int grow0 = i0 + 32*w + lr;       // row owned for h=0
    int grow1 = grow0 + 16;           // row owned for h=1
    const unsigned short* gA0 = snb + (size_t)grow0 * DIM + 8*g;
    const unsigned short* gA1 = snb + (size_t)grow1 * DIM + 8*g;

    // staging source: lane l fetches B[c0 + 32w + 8j + (l>>3)][ ((l&7)^(l>>3))*8 .. +8 ]
    const unsigned short* gB = snb + (size_t)(c0 + 32*w + (lane >> 3)) * DIM
                                   + ((lane & 7) ^ (lane >> 3)) * 8;
    // read-side swizzled slot offsets (elements)
    const int off0e = ((g ^ (lr & 7)) * 8);
    const int off1e = off0e ^ 32;

    f32x4 acc[2][8];
    #pragma unroll
    for (int n = 0; n < 8; ++n) {
        acc[0][n] = (f32x4){0.f,0.f,0.f,0.f};
        acc[1][n] = (f32x4){0.f,0.f,0.f,0.f};
    }

    // prologue: stage k-tile 0 into buf 0 + A(0) into reg set 0
    {
        unsigned short* dst = &Bbuf[0][32*w][0];
        gl16(gB,            dst);
        gl16(gB +  8*DIM,   dst +  8*BK2);
        gl16(gB + 16*DIM,   dst + 16*BK2);
        gl16(gB + 24*DIM,   dst + 24*BK2);
    }
    bf16x8 aA[2][4];
    aA[0][0] = *reinterpret_cast<const bf16x8*>(gA0);
    aA[0][1] = *reinterpret_cast<const bf16x8*>(gA0 + 32);
    aA[0][2] = *reinterpret_cast<const bf16x8*>(gA1);
    aA[0][3] = *reinterpret_cast<const bf16x8*>(gA1 + 32);
    __syncthreads();   // full drain: buf0 + A(0) valid

    #pragma unroll
    for (int it = 0; it < 8; ++it) {
        const int cur = it & 1, nxt = cur ^ 1;
        if (it > 0) {
            // stage(it)+A(it) were issued LAST iter and had the whole MFMA phase
            // to land -> near-free wait. Raw barrier: no compiler-forced drain point.
            asm volatile("s_waitcnt vmcnt(0)" ::: "memory");
            __builtin_amdgcn_sched_barrier(0);
            __builtin_amdgcn_s_barrier();
            __builtin_amdgcn_sched_barrier(0);
        }
        if (it < 7) {   // issue next tile's stage + A loads; drained top of next iter
            unsigned short* dst = &Bbuf[nxt][32*w][0];
            const unsigned short* src = gB + (it + 1) * BK2;
            gl16(src,            dst);
            gl16(src +  8*DIM,   dst +  8*BK2);
            gl16(src + 16*DIM,   dst + 16*BK2);
            gl16(src + 24*DIM,   dst + 24*BK2);
            const int k1 = (it + 1) * BK2;
            aA[nxt][0] = *reinterpret_cast<const bf16x8*>(gA0 + k1);
            aA[nxt][1] = *reinterpret_cast<const bf16x8*>(gA0 + k1 + 32);
            aA[nxt][2] = *reinterpret_cast<const bf16x8*>(gA1 + k1);
            aA[nxt][3] = *reinterpret_cast<const bf16x8*>(gA1 + k1 + 32);
        }
        const unsigned short* Bb = &Bbuf[cur][0][0];
        #pragma unroll
        for (int n = 0; n < 8; ++n) {
            const unsigned short* rbase = Bb + (16*n + lr) * BK2;
            bf16x8 b0 = *reinterpret_cast<const bf16x8*>(rbase + off0e);
            bf16x8 b1 = *reinterpret_cast<const bf16x8*>(rbase + off1e);
            acc[0][n] = __builtin_amdgcn_mfma_f32_16x16x32_bf16(b0, aA[cur][0], acc[0][n], 0, 0, 0);
            acc[1][n] = __builtin_amdgcn_mfma_f32_16x16x32_bf16(b0, aA[cur][2], acc[1][n], 0, 0, 0);
            acc[0][n] = __builtin_amdgcn_mfma_f32_16x16x32_bf16(b1, aA[cur][1], acc[0][n], 0, 0, 0);
            acc[1][n] = __builtin_amdgcn_mfma_f32_16x16x32_bf16(b1, aA[cur][3], acc[1][n], 0, 0, 0);
        }
    }

    // ---- symmetric threshold harvest (r11 measured-best form): hit (i,j,v) with
    // j>i -> row i gets j, row j gets i. gc>grow covers off-diag + diag upper half.
    #pragma unroll
    for (int n = 0; n < 8; ++n) {
        #pragma unroll
        for (int h = 0; h < 2; ++h) {
            f32x4 v4 = acc[h][n];
            float m4 = fmaxf(fmaxf(v4[0], v4[1]), fmaxf(v4[2], v4[3]));
            if (m4 > THR) {
                int grow = h ? grow1 : grow0;
                int gcb = c0 + 16*n + 4*g;
                #pragma unroll
                for (int e = 0; e < 4; ++e) {
                    float v = v4[e]; int gc = gcb + e;
                    if (v > THR && gc > grow) {
                        int s = atomicAdd(&cnt[grow], 1);
                        if (s < CAP) {
                            cval[(size_t)grow * CAP + s] = v;
                            cidx[(size_t)grow * CAP + s] = gc;
                        }
                        int s2 = atomicAdd(&cnt[gc], 1);
                        if (s2 < CAP) {
                            cval[(size_t)gc * CAP + s2] = v;
                            cidx[(size_t)gc * CAP + s2] = grow;
                        }
                    }
                }
            }
        }
    }
}

// ---------------- kernel 3: fused top-16 select + fp32 rescore + GNN pass 1 ----------------
__global__ __launch_bounds__(256) void k_selgnn1(const float* __restrict__ cval,
                                                 const int* __restrict__ cidx,
                                                 const int* __restrict__ cnt,
                                                 const float* __restrict__ sn,
                                                 const long long* __restrict__ labels,
                                                 const float* __restrict__ Wm,
                                                 float* __restrict__ wv,
                                                 int* __restrict__ wi,
                                                 float* __restrict__ h0) {
    int wq = threadIdx.x >> 6, lane = threadIdx.x & 63;
    int row = blockIdx.x * 4 + wq;
    int nc = cnt[row]; if (nc > CAP) nc = CAP;
    const float* pv = cval + (size_t)row * CAP;
    const int*   pi = cidx + (size_t)row * CAP;
    float s0v = (lane < nc) ? pv[lane] : -1e30f;
    int   s0i = (lane < nc) ? pi[lane] : 0x7fffffff;
    float s1v = (lane + 64 < nc) ? pv[lane + 64] : -1e30f;
    int   s1i = (lane + 64 < nc) ? pi[lane + 64] : 0x7fffffff;

    // ---- tournament top-16 (wave-uniform result in cwv/cwi) ----
    float cwv[NCAND]; int cwi[NCAND];
    #pragma unroll
    for (int t = 0; t < NCAND; ++t) {
        bool p0 = (s0v > s1v) || (s0v == s1v && s0i < s1i);
        float bv = p0 ? s0v : s1v;
        int   bi = p0 ? s0i : s1i;
        #pragma unroll
        for (int o = 32; o > 0; o >>= 1) {
            float ov = __shfl_xor(bv, o);
            int   oi = __shfl_xor(bi, o);
            if (ov > bv || (ov == bv && oi < bi)) { bv = ov; bi = oi; }
        }
        cwv[t] = bv; cwi[t] = bi;
        if (s0i == bi) { s0v = -1e30f; s0i = 0x7fffffff; }
        if (s1i == bi) { s1v = -1e30f; s1i = 0x7fffffff; }
    }

    // ---- exact fp32 rescore: group q = lane>>4 handles candidate 4j+q in round j
    int qg = lane >> 4, r = lane & 15;
    float4 qv[8];
    #pragma unroll
    for (int u = 0; u < 8; ++u)
        qv[u] = *reinterpret_cast<const float4*>(sn + (size_t)row * DIM + 32*r + 4*u);

    float scJ[4]; int idJ[4];
    #pragma unroll
    for (int j = 0; j < 4; ++j) {
        float v_j = (qg == 0) ? cwv[4*j+0] : (qg == 1) ? cwv[4*j+1]
                  : (qg == 2) ? cwv[4*j+2] : cwv[4*j+3];
        int   i_j = (qg == 0) ? cwi[4*j+0] : (qg == 1) ? cwi[4*j+1]
                  : (qg == 2) ? cwi[4*j+2] : cwi[4*j+3];
        bool valid = (v_j > -1e29f);
        int cid = valid ? i_j : row;
        const float* cp = sn + (size_t)cid * DIM + 32*r;
        float d = 0.f;
        #pragma unroll
        for (int u = 0; u < 8; ++u) {
            float4 a = *reinterpret_cast<const float4*>(cp + 4*u);
            d += qv[u].x*a.x + qv[u].y*a.y + qv[u].z*a.z + qv[u].w*a.w;
        }
        d += __shfl_xor(d, 1); d += __shfl_xor(d, 2);
        d += __shfl_xor(d, 4); d += __shfl_xor(d, 8);
        scJ[j] = valid ? d : -1e30f;
        idJ[j] = i_j;
    }
    // redistribute: lane t<16 takes candidate t (round t>>2, group t&3)
    int srcl = 16 * (lane & 3);
    float rs0 = __shfl(scJ[0], srcl), rs1 = __shfl(scJ[1], srcl);
    float rs2 = __shfl(scJ[2], srcl), rs3 = __shfl(scJ[3], srcl);
    int   ri0 = __shfl(idJ[0], srcl), ri1 = __shfl(idJ[1], srcl);
    int   ri2 = __shfl(idJ[2], srcl), ri3 = __shfl(idJ[3], srcl);
    int jj = (lane >> 2) & 3;
    float dmine = (jj == 0) ? rs0 : (jj == 1) ? rs1 : (jj == 2) ? rs2 : rs3;
    int   cmine = (jj == 0) ? ri0 : (jj == 1) ? ri1 : (jj == 2) ? ri2 : ri3;

    int rank = 0;
    #pragma unroll
    for (int j = 0; j < NCAND; ++j) {
        float dj = __shfl(dmine, j);
        int   cj = __shfl(cmine, j);
        if (dj > dmine || (dj == dmine && cj < cmine)) ++rank;
    }
    if (lane < NCAND && rank < KNB && dmine > -1e29f) {
        wv[(size_t)row * KNB + rank] = dmine;
        wi[(size_t)row * KNB + rank] = cmine;
    }

    // ---- GNN pass 1 (implicit one-hot): a[c] = sum_k wk * [label(id_k)==c] ----
    float a = 0.f, a64 = 0.f;
    #pragma unroll
    for (int t = 0; t < NCAND; ++t) {
        float d  = __shfl(dmine, t);
        int   id = __shfl(cmine, t);
        int   rk = __shfl(rank, t);
        if (rk < KNB && d > -1e29f && id < QUEUE) {
            int lbl = (int)labels[id];
            a   += (lbl == lane) ? d : 0.f;
            a64 += (lbl == 64)   ? d : 0.f;
        }
    }
    float l = 0.f, l64 = 0.f;
    #pragma unroll 8
    for (int cc = 0; cc < 64; ++cc) {
        float ac = __shfl(a, cc);
        l   = fmaf(ac, Wm[cc * NCLS + lane], l);
        l64 = fmaf(ac, Wm[cc * NCLS + 64],  l64);
    }
    l   = fmaf(a64, Wm[64 * NCLS + lane], l);
    l64 = fmaf(a64, Wm[64 * NCLS + 64],  l64);
    float m = l;
    #pragma unroll
    for (int o = 32; o > 0; o >>= 1) m = fmaxf(m, __shfl_xor(m, o));
    m = fmaxf(m, l64);
    float e = expf(l - m);
    float s = e;
    #pragma unroll
    for (int o = 32; o > 0; o >>= 1) s += __shfl_xor(s, o);
    float e64 = expf(l64 - m);
    s += e64;
    h0[(size_t)row * NCLS + lane] = e / s;
    if (lane == 0) h0[(size_t)row * NCLS + 64] = e64 / s;
}

// ---------------- kernel 4: GNN pass 2, ONLY for query-neighbor rows ----------------
// wave p handles pair (q = p/10, k = p%10): row = wi[(QUEUE+q)*KNB + k].
// Duplicate rows recompute identical values (benign).
__global__ __launch_bounds__(256) void k_gnnw(const float* __restrict__ wv,
                                              const int* __restrict__ wi,
                                              const float* __restrict__ hin,
                                              const float* __restrict__ Wm,
                                              float* __restrict__ hout) {
    int wq = threadIdx.x >> 6, lane = threadIdx.x & 63;
    int p = blockIdx.x * 4 + wq;               // 0..2559
    int q = p / KNB, k2 = p - q * KNB;
    int row = wi[(size_t)(QUEUE + q) * KNB + k2];
    float a = 0.f, a64 = 0.f;
    #pragma unroll
    for (int k = 0; k < KNB; ++k) {
        float wk = wv[(size_t)row * KNB + k];
        int   id = wi[(size_t)row * KNB + k];
        a += wk * hin[(size_t)id * NCLS + lane];
        if (lane == 0) a64 += wk * hin[(size_t)id * NCLS + 64];
    }
    a64 = __shfl(a64, 0);
    float l = 0.f, l64 = 0.f;
    #pragma unroll 8
    for (int cc = 0; cc < 64; ++cc) {
        float ac = __shfl(a, cc);
        l   = fmaf(ac, Wm[cc * NCLS + lane], l);
        l64 = fmaf(ac, Wm[cc * NCLS + 64],  l64);
    }
    l   = fmaf(a64, Wm[64 * NCLS + lane], l);
    l64 = fmaf(a64, Wm[64 * NCLS + 64],  l64);
    float m = l;
    #pragma unroll
    for (int o = 32; o > 0; o >>= 1) m = fmaxf(m, __shfl_xor(m, o));
    m = fmaxf(m, l64);
    float e = expf(l - m);
    float s = e;
    #pragma unroll
    for (int o = 32; o > 0; o >>= 1) s += __shfl_xor(s, o);
    float e64 = expf(l64 - m);
    s += e64;
    hout[(size_t)row * NCLS + lane] = e / s;
    if (lane == 0) hout[(size_t)row * NCLS + 64] = e64 / s;
}

// ---------------- kernel 5: final pass (queries) + confidence/argmax ----------------
__global__ __launch_bounds__(256) void k_finalw(const float* __restrict__ wv,
                                                const int* __restrict__ wi,
                                                const float* __restrict__ hin,
                                                const float* __restrict__ Wm,
                                                float* __restrict__ out) {
    int wq = threadIdx.x >> 6, lane = threadIdx.x & 63;
    int qi = blockIdx.x * 4 + wq;
    int row = QUEUE + qi;
    float a = 0.f, a64 = 0.f;
    #pragma unroll
    for (int k = 0; k < KNB; ++k) {
        float wk = wv[(size_t)row * KNB + k];
        int   id = wi[(size_t)row * KNB + k];
        a += wk * hin[(size_t)id * NCLS + lane];
        if (lane == 0) a64 += wk * hin[(size_t)id * NCLS + 64];
    }
    a64 = __shfl(a64, 0);
    float l = 0.f, l64 = 0.f;
    #pragma unroll 8
    for (int cc = 0; cc < 64; ++cc) {
        float ac = __shfl(a, cc);
        l   = fmaf(ac, Wm[cc * NCLS + lane], l);
        l64 = fmaf(ac, Wm[cc * NCLS + 64],  l64);
    }
    l   = fmaf(a64, Wm[64 * NCLS + lane], l);
    l64 = fmaf(a64, Wm[64 * NCLS + 64],  l64);
    float bv = l; int bi = lane;
    #pragma unroll
    for (int o = 32; o > 0; o >>= 1) {
        float ov = __shfl_xor(bv, o);
        int   oi = __shfl_xor(bi, o);
        if (ov > bv || (ov == bv && oi < bi)) { bv = ov; bi = oi; }
    }
    if (l64 > bv) { bv = l64; bi = 64; }
    float e = expf(l - bv);
    float s = e;
    #pragma unroll
    for (int o = 32; o > 0; o >>= 1) s += __shfl_xor(s, o);
    s += expf(l64 - bv);
    if (lane == 0) {
        out[qi]         = 1.0f / s;     // confidence = max(softmax)
        out[BATCH + qi] = (float)bi;    // predict
    }
}

// ---------------- host launcher ----------------
extern "C" void kernel_launch(void* const* d_in, const int* in_sizes, int n_in,
                              void* d_out, int out_size, void* d_ws, size_t ws_size,
                              hipStream_t stream) {
    const float*     x      = (const float*)d_in[0];      // (256,512)
    const float*     memory = (const float*)d_in[1];      // (8192,512)
    const float*     W      = (const float*)d_in[2];      // (65,65)
    const long long* labels = (const long long*)d_in[3];  // (8192,)

    float*          sn  = (float*)d_ws;                                    // NROW*DIM f32
    unsigned short* snb = (unsigned short*)(sn + (size_t)NROW * DIM);      // NROW*DIM bf16
    float* cval = (float*)(snb + (size_t)NROW * DIM);                      // NROW*CAP
    int*   cidx = (int*)(cval + (size_t)NROW * CAP);                       // NROW*CAP
    int*   cnt  = (int*)(cidx + (size_t)NROW * CAP);                       // NROW
    float* wv   = (float*)(cnt + NROW);                                    // NROW*KNB
    int*   wi   = (int*)(wv + (size_t)NROW * KNB);                         // NROW*KNB
    float* h0   = (float*)(wi + (size_t)NROW * KNB);                       // NROW*NCLS
    float* h1   = h0 + (size_t)NROW * NCLS;                                // NROW*NCLS

    hipMemsetAsync(cnt, 0, NROW * sizeof(int), stream);
    k_norm<<<NROW, 128, 0, stream>>>(memory, x, sn, snb);
    k_simscan<<<NTRI, 256, 0, stream>>>(snb, cval, cidx, cnt);
    k_selgnn1<<<NROW / 4, 256, 0, stream>>>(cval, cidx, cnt, sn, labels, W, wv, wi, h0);
    k_gnnw<<<640, 256, 0, stream>>>(wv, wi, h0, W, h1);
    k_finalw<<<BATCH / 4, 256, 0, stream>>>(wv, wi, h1, W, (float*)d_out);
}

// Round 14
// 228.899 us; speedup vs baseline: 1.1923x; 1.0104x over previous
//
#include <hip/hip_runtime.h>
#include <math.h>

#define QUEUE 8192
#define BATCH 256
#define NROW  8448        // QUEUE + BATCH
#define DIM   512
#define NCLS  65
#define KNB   10
#define NCAND 16          // rescored candidate set per row
#define BM 128
#define BN 128
#define BK2 64            // K-step (two 32-deep MFMA halves)
#define NBAND  66         // NROW / BM
#define NTRI  2211        // NBAND*(NBAND+1)/2 upper-triangle tiles
#define GSB 11            // supertile edge (tiles)
#define CAP 128           // candidate slots per row
#define THR 0.11f         // bf16-sim candidate threshold (~40 sigma margin vs true 10th)

typedef __attribute__((ext_vector_type(8))) short bf16x8;
typedef __attribute__((ext_vector_type(4))) float f32x4;

__device__ __forceinline__ unsigned short f2bf(float f) {
    unsigned int u = __float_as_uint(f);
    unsigned int r = (u + 0x7fffu + ((u >> 16) & 1u)) >> 16;   // RTNE
    return (unsigned short)r;
}

// async global->LDS, 16B per lane; dest = wave-uniform base + lane*16 (linear)
__device__ __forceinline__ void gl16(const unsigned short* g, unsigned short* l) {
    __builtin_amdgcn_global_load_lds(
        (const __attribute__((address_space(1))) unsigned int*)g,
        (__attribute__((address_space(3))) unsigned int*)l, 16, 0, 0);
}

// ---------------- kernel 1: row normalize (fp32 + bf16 copies) ----------------
__global__ __launch_bounds__(128) void k_norm(const float* __restrict__ mem,
                                              const float* __restrict__ xq,
                                              float* __restrict__ sn,
                                              unsigned short* __restrict__ snb) {
    int row = blockIdx.x;
    const float* src = (row < QUEUE) ? (mem + (size_t)row * DIM)
                                     : (xq + (size_t)(row - QUEUE) * DIM);
    float4 v = reinterpret_cast<const float4*>(src)[threadIdx.x];
    float ss = v.x*v.x + v.y*v.y + v.z*v.z + v.w*v.w;
    #pragma unroll
    for (int o = 32; o > 0; o >>= 1) ss += __shfl_xor(ss, o);
    __shared__ float s2[2];
    if ((threadIdx.x & 63) == 0) s2[threadIdx.x >> 6] = ss;
    __syncthreads();
    float nrm = fmaxf(sqrtf(s2[0] + s2[1]), 1e-12f);
    float4 o4 = make_float4(v.x / nrm, v.y / nrm, v.z / nrm, v.w / nrm);
    reinterpret_cast<float4*>(sn + (size_t)row * DIM)[threadIdx.x] = o4;
    ushort4 b4;
    b4.x = f2bf(o4.x); b4.y = f2bf(o4.y); b4.z = f2bf(o4.z); b4.w = f2bf(o4.w);
    reinterpret_cast<ushort4*>(snb + (size_t)row * DIM)[threadIdx.x] = b4;
}

// ---------------- kernel 2: bf16 MFMA sim, upper triangle, supertile-ordered,
// 2-DEEP pipelined K-loop (T4 counted vmcnt): 3 LDS buffers; per iter wait
// vmcnt(8) (tile t's 8 ops are oldest; t+1/t+2 stay in flight), raw barrier,
// issue stage(t+2)+A(t+2), MFMA on buf[t%3]. Never drain to 0 mid-loop.
__global__ __launch_bounds__(256, 4) void k_simscan(const unsigned short* __restrict__ snb,
                                                    float* __restrict__ cval,
                                                    int* __restrict__ cidx,
                                                    int* __restrict__ cnt) {
    __shared__ unsigned short Bbuf[3][BN][BK2];   // 3 x 16 KB, linear

    // bijective XCD-contiguous remap (m204)
    int wg = blockIdx.x;
    {
        const int q = NTRI / 8, r = NTRI % 8;     // 276, 3
        int x = wg & 7, idx = wg >> 3;
        wg = (x < r ? x * (q + 1) : r * (q + 1) + (x - r) * q) + idx;
    }
    // supertile decode (G=11): wg<396 -> diagonal supertile (triangular inner);
    // else off-diagonal supertile pair (I<J), 121 inner tiles.
    int band, chunk;
    if (wg < 6 * 66) {
        int I = wg / 66, t = wg % 66;
        int r2 = 0;
        while (t >= GSB - r2) { t -= GSB - r2; ++r2; }
        band  = I * GSB + r2;
        chunk = band + t;
    } else {
        int e = (wg - 396) / 121, t = (wg - 396) % 121;
        int I = 0, rem = e;
        while (rem >= 5 - I) { rem -= 5 - I; ++I; }
        int J = I + 1 + rem;
        band  = I * GSB + t / GSB;
        chunk = J * GSB + t % GSB;
    }
    int i0 = band * BM;
    int c0 = chunk * BN;

    int tid  = threadIdx.x;
    int w    = tid >> 6;
    int lane = tid & 63;
    int lr   = lane & 15;
    int g    = lane >> 4;       // 0..3

    int grow0 = i0 + 32*w + lr;       // row owned for h=0
    int grow1 = grow0 + 16;           // row owned for h=1
    const unsigned short* gA0 = snb + (size_t)grow0 * DIM + 8*g;
    const unsigned short* gA1 = snb + (size_t)grow1 * DIM + 8*g;

    // staging source: lane l fetches B[c0 + 32w + 8j + (l>>3)][ ((l&7)^(l>>3))*8 .. +8 ]
    const unsigned short* gB = snb + (size_t)(c0 + 32*w + (lane >> 3)) * DIM
                                   + ((lane & 7) ^ (lane >> 3)) * 8;
    // read-side swizzled slot offsets (elements)
    const int off0e = ((g ^ (lr & 7)) * 8);
    const int off1e = off0e ^ 32;

    f32x4 acc[2][8];
    #pragma unroll
    for (int n = 0; n < 8; ++n) {
        acc[0][n] = (f32x4){0.f,0.f,0.f,0.f};
        acc[1][n] = (f32x4){0.f,0.f,0.f,0.f};
    }

    // prologue: issue tiles 0 and 1 (stage + A), 16 VMEM ops outstanding
    bf16x8 aA[3][4];
    {
        unsigned short* dst = &Bbuf[0][32*w][0];
        gl16(gB,            dst);
        gl16(gB +  8*DIM,   dst +  8*BK2);
        gl16(gB + 16*DIM,   dst + 16*BK2);
        gl16(gB + 24*DIM,   dst + 24*BK2);
        aA[0][0] = *reinterpret_cast<const bf16x8*>(gA0);
        aA[0][1] = *reinterpret_cast<const bf16x8*>(gA0 + 32);
        aA[0][2] = *reinterpret_cast<const bf16x8*>(gA1);
        aA[0][3] = *reinterpret_cast<const bf16x8*>(gA1 + 32);
    }
    {
        unsigned short* dst = &Bbuf[1][32*w][0];
        const unsigned short* src = gB + BK2;
        gl16(src,            dst);
        gl16(src +  8*DIM,   dst +  8*BK2);
        gl16(src + 16*DIM,   dst + 16*BK2);
        gl16(src + 24*DIM,   dst + 24*BK2);
        aA[1][0] = *reinterpret_cast<const bf16x8*>(gA0 + BK2);
        aA[1][1] = *reinterpret_cast<const bf16x8*>(gA0 + BK2 + 32);
        aA[1][2] = *reinterpret_cast<const bf16x8*>(gA1 + BK2);
        aA[1][3] = *reinterpret_cast<const bf16x8*>(gA1 + BK2 + 32);
    }

    #pragma unroll
    for (int it = 0; it < 8; ++it) {
        const int cur = it % 3;
        // tile(it)'s 8 ops are the OLDEST outstanding; keep t+1/t+2 in flight.
        if (it < 7) {
            asm volatile("s_waitcnt vmcnt(8)" ::: "memory");
        } else {
            asm volatile("s_waitcnt vmcnt(0)" ::: "memory");
        }
        __builtin_amdgcn_sched_barrier(0);
        __builtin_amdgcn_s_barrier();     // all waves' tile(it) complete
        __builtin_amdgcn_sched_barrier(0);
        if (it < 6) {   // issue tile it+2 into buf[(it+2)%3] (read last at iter it-1)
            const int nx = (it + 2) % 3;
            unsigned short* dst = &Bbuf[nx][32*w][0];
            const unsigned short* src = gB + (it + 2) * BK2;
            gl16(src,            dst);
            gl16(src +  8*DIM,   dst +  8*BK2);
            gl16(src + 16*DIM,   dst + 16*BK2);
            gl16(src + 24*DIM,   dst + 24*BK2);
            const int k2 = (it + 2) * BK2;
            aA[nx][0] = *reinterpret_cast<const bf16x8*>(gA0 + k2);
            aA[nx][1] = *reinterpret_cast<const bf16x8*>(gA0 + k2 + 32);
            aA[nx][2] = *reinterpret_cast<const bf16x8*>(gA1 + k2);
            aA[nx][3] = *reinterpret_cast<const bf16x8*>(gA1 + k2 + 32);
        }
        const unsigned short* Bb = &Bbuf[cur][0][0];
        #pragma unroll
        for (int n = 0; n < 8; ++n) {
            const unsigned short* rbase = Bb + (16*n + lr) * BK2;
            bf16x8 b0 = *reinterpret_cast<const bf16x8*>(rbase + off0e);
            bf16x8 b1 = *reinterpret_cast<const bf16x8*>(rbase + off1e);
            acc[0][n] = __builtin_amdgcn_mfma_f32_16x16x32_bf16(b0, aA[cur][0], acc[0][n], 0, 0, 0);
            acc[1][n] = __builtin_amdgcn_mfma_f32_16x16x32_bf16(b0, aA[cur][2], acc[1][n], 0, 0, 0);
            acc[0][n] = __builtin_amdgcn_mfma_f32_16x16x32_bf16(b1, aA[cur][1], acc[0][n], 0, 0, 0);
            acc[1][n] = __builtin_amdgcn_mfma_f32_16x16x32_bf16(b1, aA[cur][3], acc[1][n], 0, 0, 0);
        }
    }

    // ---- symmetric threshold harvest: hit (i,j,v) with j>i -> row i gets j,
    // row j gets i. gc>grow covers off-diag + diag upper half (no self).
    #pragma unroll
    for (int n = 0; n < 8; ++n) {
        #pragma unroll
        for (int h = 0; h < 2; ++h) {
            f32x4 v4 = acc[h][n];
            float m4 = fmaxf(fmaxf(v4[0], v4[1]), fmaxf(v4[2], v4[3]));
            if (m4 > THR) {
                int grow = h ? grow1 : grow0;
                int gcb = c0 + 16*n + 4*g;
                #pragma unroll
                for (int e = 0; e < 4; ++e) {
                    float v = v4[e]; int gc = gcb + e;
                    if (v > THR && gc > grow) {
                        int s = atomicAdd(&cnt[grow], 1);
                        if (s < CAP) {
                            cval[(size_t)grow * CAP + s] = v;
                            cidx[(size_t)grow * CAP + s] = gc;
                        }
                        int s2 = atomicAdd(&cnt[gc], 1);
                        if (s2 < CAP) {
                            cval[(size_t)gc * CAP + s2] = v;
                            cidx[(size_t)gc * CAP + s2] = grow;
                        }
                    }
                }
            }
        }
    }
}

// ---------------- kernel 3: fused top-16 select + fp32 rescore + GNN pass 1 ----------------
__global__ __launch_bounds__(256) void k_selgnn1(const float* __restrict__ cval,
                                                 const int* __restrict__ cidx,
                                                 const int* __restrict__ cnt,
                                                 const float* __restrict__ sn,
                                                 const long long* __restrict__ labels,
                                                 const float* __restrict__ Wm,
                                                 float* __restrict__ wv,
                                                 int* __restrict__ wi,
                                                 float* __restrict__ h0) {
    int wq = threadIdx.x >> 6, lane = threadIdx.x & 63;
    int row = blockIdx.x * 4 + wq;
    int nc = cnt[row]; if (nc > CAP) nc = CAP;
    const float* pv = cval + (size_t)row * CAP;
    const int*   pi = cidx + (size_t)row * CAP;
    float s0v = (lane < nc) ? pv[lane] : -1e30f;
    int   s0i = (lane < nc) ? pi[lane] : 0x7fffffff;
    float s1v = (lane + 64 < nc) ? pv[lane + 64] : -1e30f;
    int   s1i = (lane + 64 < nc) ? pi[lane + 64] : 0x7fffffff;

    // ---- tournament top-16 (wave-uniform result in cwv/cwi) ----
    float cwv[NCAND]; int cwi[NCAND];
    #pragma unroll
    for (int t = 0; t < NCAND; ++t) {
        bool p0 = (s0v > s1v) || (s0v == s1v && s0i < s1i);
        float bv = p0 ? s0v : s1v;
        int   bi = p0 ? s0i : s1i;
        #pragma unroll
        for (int o = 32; o > 0; o >>= 1) {
            float ov = __shfl_xor(bv, o);
            int   oi = __shfl_xor(bi, o);
            if (ov > bv || (ov == bv && oi < bi)) { bv = ov; bi = oi; }
        }
        cwv[t] = bv; cwi[t] = bi;
        if (s0i == bi) { s0v = -1e30f; s0i = 0x7fffffff; }
        if (s1i == bi) { s1v = -1e30f; s1i = 0x7fffffff; }
    }

    // ---- exact fp32 rescore: group q = lane>>4 handles candidate 4j+q in round j
    int qg = lane >> 4, r = lane & 15;
    float4 qv[8];
    #pragma unroll
    for (int u = 0; u < 8; ++u)
        qv[u] = *reinterpret_cast<const float4*>(sn + (size_t)row * DIM + 32*r + 4*u);

    float scJ[4]; int idJ[4];
    #pragma unroll
    for (int j = 0; j < 4; ++j) {
        float v_j = (qg == 0) ? cwv[4*j+0] : (qg == 1) ? cwv[4*j+1]
                  : (qg == 2) ? cwv[4*j+2] : cwv[4*j+3];
        int   i_j = (qg == 0) ? cwi[4*j+0] : (qg == 1) ? cwi[4*j+1]
                  : (qg == 2) ? cwi[4*j+2] : cwi[4*j+3];
        bool valid = (v_j > -1e29f);
        int cid = valid ? i_j : row;
        const float* cp = sn + (size_t)cid * DIM + 32*r;
        float d = 0.f;
        #pragma unroll
        for (int u = 0; u < 8; ++u) {
            float4 a = *reinterpret_cast<const float4*>(cp + 4*u);
            d += qv[u].x*a.x + qv[u].y*a.y + qv[u].z*a.z + qv[u].w*a.w;
        }
        d += __shfl_xor(d, 1); d += __shfl_xor(d, 2);
        d += __shfl_xor(d, 4); d += __shfl_xor(d, 8);
        scJ[j] = valid ? d : -1e30f;
        idJ[j] = i_j;
    }
    // redistribute: lane t<16 takes candidate t (round t>>2, group t&3)
    int srcl = 16 * (lane & 3);
    float rs0 = __shfl(scJ[0], srcl), rs1 = __shfl(scJ[1], srcl);
    float rs2 = __shfl(scJ[2], srcl), rs3 = __shfl(scJ[3], srcl);
    int   ri0 = __shfl(idJ[0], srcl), ri1 = __shfl(idJ[1], srcl);
    int   ri2 = __shfl(idJ[2], srcl), ri3 = __shfl(idJ[3], srcl);
    int jj = (lane >> 2) & 3;
    float dmine = (jj == 0) ? rs0 : (jj == 1) ? rs1 : (jj == 2) ? rs2 : rs3;
    int   cmine = (jj == 0) ? ri0 : (jj == 1) ? ri1 : (jj == 2) ? ri2 : ri3;

    int rank = 0;
    #pragma unroll
    for (int j = 0; j < NCAND; ++j) {
        float dj = __shfl(dmine, j);
        int   cj = __shfl(cmine, j);
        if (dj > dmine || (dj == dmine && cj < cmine)) ++rank;
    }
    if (lane < NCAND && rank < KNB && dmine > -1e29f) {
        wv[(size_t)row * KNB + rank] = dmine;
        wi[(size_t)row * KNB + rank] = cmine;
    }

    // ---- GNN pass 1 (implicit one-hot): a[c] = sum_k wk * [label(id_k)==c] ----
    float a = 0.f, a64 = 0.f;
    #pragma unroll
    for (int t = 0; t < NCAND; ++t) {
        float d  = __shfl(dmine, t);
        int   id = __shfl(cmine, t);
        int   rk = __shfl(rank, t);
        if (rk < KNB && d > -1e29f && id < QUEUE) {
            int lbl = (int)labels[id];
            a   += (lbl == lane) ? d : 0.f;
            a64 += (lbl == 64)   ? d : 0.f;
        }
    }
    float l = 0.f, l64 = 0.f;
    #pragma unroll 8
    for (int cc = 0; cc < 64; ++cc) {
        float ac = __shfl(a, cc);
        l   = fmaf(ac, Wm[cc * NCLS + lane], l);
        l64 = fmaf(ac, Wm[cc * NCLS + 64],  l64);
    }
    l   = fmaf(a64, Wm[64 * NCLS + lane], l);
    l64 = fmaf(a64, Wm[64 * NCLS + 64],  l64);
    float m = l;
    #pragma unroll
    for (int o = 32; o > 0; o >>= 1) m = fmaxf(m, __shfl_xor(m, o));
    m = fmaxf(m, l64);
    float e = expf(l - m);
    float s = e;
    #pragma unroll
    for (int o = 32; o > 0; o >>= 1) s += __shfl_xor(s, o);
    float e64 = expf(l64 - m);
    s += e64;
    h0[(size_t)row * NCLS + lane] = e / s;
    if (lane == 0) h0[(size_t)row * NCLS + 64] = e64 / s;
}

// ---------------- kernel 4: GNN pass 2, ONLY for query-neighbor rows ----------------
__global__ __launch_bounds__(256) void k_gnnw(const float* __restrict__ wv,
                                              const int* __restrict__ wi,
                                              const float* __restrict__ hin,
                                              const float* __restrict__ Wm,
                                              float* __restrict__ hout) {
    int wq = threadIdx.x >> 6, lane = threadIdx.x & 63;
    int p = blockIdx.x * 4 + wq;               // 0..2559
    int q = p / KNB, k2 = p - q * KNB;
    int row = wi[(size_t)(QUEUE + q) * KNB + k2];
    float a = 0.f, a64 = 0.f;
    #pragma unroll
    for (int k = 0; k < KNB; ++k) {
        float wk = wv[(size_t)row * KNB + k];
        int   id = wi[(size_t)row * KNB + k];
        a += wk * hin[(size_t)id * NCLS + lane];
        if (lane == 0) a64 += wk * hin[(size_t)id * NCLS + 64];
    }
    a64 = __shfl(a64, 0);
    float l = 0.f, l64 = 0.f;
    #pragma unroll 8
    for (int cc = 0; cc < 64; ++cc) {
        float ac = __shfl(a, cc);
        l   = fmaf(ac, Wm[cc * NCLS + lane], l);
        l64 = fmaf(ac, Wm[cc * NCLS + 64],  l64);
    }
    l   = fmaf(a64, Wm[64 * NCLS + lane], l);
    l64 = fmaf(a64, Wm[64 * NCLS + 64],  l64);
    float m = l;
    #pragma unroll
    for (int o = 32; o > 0; o >>= 1) m = fmaxf(m, __shfl_xor(m, o));
    m = fmaxf(m, l64);
    float e = expf(l - m);
    float s = e;
    #pragma unroll
    for (int o = 32; o > 0; o >>= 1) s += __shfl_xor(s, o);
    float e64 = expf(l64 - m);
    s += e64;
    hout[(size_t)row * NCLS + lane] = e / s;
    if (lane == 0) hout[(size_t)row * NCLS + 64] = e64 / s;
}

// ---------------- kernel 5: final pass (queries) + confidence/argmax ----------------
__global__ __launch_bounds__(256) void k_finalw(const float* __restrict__ wv,
                                                const int* __restrict__ wi,
                                                const float* __restrict__ hin,
                                                const float* __restrict__ Wm,
                                                float* __restrict__ out) {
    int wq = threadIdx.x >> 6, lane = threadIdx.x & 63;
    int qi = blockIdx.x * 4 + wq;
    int row = QUEUE + qi;
    float a = 0.f, a64 = 0.f;
    #pragma unroll
    for (int k = 0; k < KNB; ++k) {
        float wk = wv[(size_t)row * KNB + k];
        int   id = wi[(size_t)row * KNB + k];
        a += wk * hin[(size_t)id * NCLS + lane];
        if (lane == 0) a64 += wk * hin[(size_t)id * NCLS + 64];
    }
    a64 = __shfl(a64, 0);
    float l = 0.f, l64 = 0.f;
    #pragma unroll 8
    for (int cc = 0; cc < 64; ++cc) {
        float ac = __shfl(a, cc);
        l   = fmaf(ac, Wm[cc * NCLS + lane], l);
        l64 = fmaf(ac, Wm[cc * NCLS + 64],  l64);
    }
    l   = fmaf(a64, Wm[64 * NCLS + lane], l);
    l64 = fmaf(a64, Wm[64 * NCLS + 64],  l64);
    float bv = l; int bi = lane;
    #pragma unroll
    for (int o = 32; o > 0; o >>= 1) {
        float ov = __shfl_xor(bv, o);
        int   oi = __shfl_xor(bi, o);
        if (ov > bv || (ov == bv && oi < bi)) { bv = ov; bi = oi; }
    }
    if (l64 > bv) { bv = l64; bi = 64; }
    float e = expf(l - bv);
    float s = e;
    #pragma unroll
    for (int o = 32; o > 0; o >>= 1) s += __shfl_xor(s, o);
    s += expf(l64 - bv);
    if (lane == 0) {
        out[qi]         = 1.0f / s;     // confidence = max(softmax)
        out[BATCH + qi] = (float)bi;    // predict
    }
}

// ---------------- host launcher ----------------
extern "C" void kernel_launch(void* const* d_in, const int* in_sizes, int n_in,
                              void* d_out, int out_size, void* d_ws, size_t ws_size,
                              hipStream_t stream) {
    const float*     x      = (const float*)d_in[0];      // (256,512)
    const float*     memory = (const float*)d_in[1];      // (8192,512)
    const float*     W      = (const float*)d_in[2];      // (65,65)
    const long long* labels = (const long long*)d_in[3];  // (8192,)

    float*          sn  = (float*)d_ws;                                    // NROW*DIM f32
    unsigned short* snb = (unsigned short*)(sn + (size_t)NROW * DIM);      // NROW*DIM bf16
    float* cval = (float*)(snb + (size_t)NROW * DIM);                      // NROW*CAP
    int*   cidx = (int*)(cval + (size_t)NROW * CAP);                       // NROW*CAP
    int*   cnt  = (int*)(cidx + (size_t)NROW * CAP);                       // NROW
    float* wv   = (float*)(cnt + NROW);                                    // NROW*KNB
    int*   wi   = (int*)(wv + (size_t)NROW * KNB);                         // NROW*KNB
    float* h0   = (float*)(wi + (size_t)NROW * KNB);                       // NROW*NCLS
    float* h1   = h0 + (size_t)NROW * NCLS;                                // NROW*NCLS

    hipMemsetAsync(cnt, 0, NROW * sizeof(int), stream);
    k_norm<<<NROW, 128, 0, stream>>>(memory, x, sn, snb);
    k_simscan<<<NTRI, 256, 0, stream>>>(snb, cval, cidx, cnt);
    k_selgnn1<<<NROW / 4, 256, 0, stream>>>(cval, cidx, cnt, sn, labels, W, wv, wi, h0);
    k_gnnw<<<640, 256, 0, stream>>>(wv, wi, h0, W, h1);
    k_finalw<<<BATCH / 4, 256, 0, stream>>>(wv, wi, h1, W, (float*)d_out);
}